// Round 8
// baseline (359.928 us; speedup 1.0000x reference)
//
#include <hip/hip_runtime.h>
#include <hip/hip_bf16.h>

#define DIM   128
#define NH    8
#define INNER 512
#define HD    64
#define BSZ   4
#define NSEQ  1024
#define PEC   32
#define BH    32   // BSZ*NH

typedef __attribute__((ext_vector_type(4))) float f32x4;
typedef __attribute__((ext_vector_type(2))) float f32x2;
typedef __attribute__((ext_vector_type(8))) short s16x8;
typedef __attribute__((ext_vector_type(4))) unsigned short u16x4;
typedef __attribute__((ext_vector_type(2))) unsigned int u32x2;

__device__ __forceinline__ unsigned short f2bf(float f) {
    unsigned u = __float_as_uint(f);
    u += 0x7fffu + ((u >> 16) & 1u);
    return (unsigned short)(u >> 16);
}

__device__ __forceinline__ float bf2f(short s) {
    return __uint_as_float(((unsigned)(unsigned short)s) << 16);
}

__device__ __forceinline__ s16x8 load8bf(const float* p) {
    f32x4 a = *(const f32x4*)p;
    f32x4 b = *(const f32x4*)(p + 4);
    s16x8 r;
    r[0] = (short)f2bf(a[0]); r[1] = (short)f2bf(a[1]);
    r[2] = (short)f2bf(a[2]); r[3] = (short)f2bf(a[3]);
    r[4] = (short)f2bf(b[0]); r[5] = (short)f2bf(b[1]);
    r[6] = (short)f2bf(b[2]); r[7] = (short)f2bf(b[3]);
    return r;
}

__device__ __forceinline__ f32x4 mfma16(s16x8 a, s16x8 b, f32x4 c) {
    return __builtin_amdgcn_mfma_f32_16x16x32_bf16(a, b, c, 0, 0, 0);
}

// ---------------------------------------------------------------------------
// K1: q/k/v projections.  q_ws,k_ws: bf16 [bh][n][d]  (q pre-scaled by 1/8)
//     vT_ws: bf16 [bh][d][n]  (transposed, bias added)
// ---------------------------------------------------------------------------
__global__ __launch_bounds__(256) void k_qkv(
    const float* __restrict__ x,
    const float* __restrict__ Wq, const float* __restrict__ Wk,
    const float* __restrict__ Wv, const float* __restrict__ bv,
    unsigned short* __restrict__ qws, unsigned short* __restrict__ kws,
    unsigned short* __restrict__ vtws)
{
    int lane = threadIdx.x & 63, wave = threadIdx.x >> 6;
    int lr = lane & 15, lg = lane >> 4;
    int ct   = blockIdx.x * 4 + wave;   // 0..95 column tile over 1536 cols
    int col0 = ct * 16;
    int m0   = blockIdx.y * 16;

    s16x8 a[4];
    const float* xrow = x + (m0 + lr) * DIM;
    #pragma unroll
    for (int kt = 0; kt < 4; ++kt) a[kt] = load8bf(xrow + kt * 32 + lg * 8);

    const float* W; int cbase; int which = col0 >> 9;
    if (which == 0)      { W = Wq; cbase = col0; }
    else if (which == 1) { W = Wk; cbase = col0 - 512; }
    else                 { W = Wv; cbase = col0 - 1024; }

    const float* wrow = W + (cbase + lr) * DIM;
    s16x8 bfr[4];
    #pragma unroll
    for (int kt = 0; kt < 4; ++kt) bfr[kt] = load8bf(wrow + kt * 32 + lg * 8);
    f32x4 acc = {0.f, 0.f, 0.f, 0.f};
    #pragma unroll
    for (int kt = 0; kt < 4; ++kt) acc = mfma16(a[kt], bfr[kt], acc);

    int colW = cbase + lr;          // 0..511 inside this projection
    int h = colW >> 6, d = colW & 63;
    int mB = m0 + lg * 4;           // 4 consecutive rows, same batch
    int b  = mB >> 10;
    int bh = b * NH + h;
    if (which == 2) {
        float bias = bv[colW];
        u16x4 pk;
        #pragma unroll
        for (int v = 0; v < 4; ++v) pk[v] = f2bf(acc[v] + bias);
        int n0 = mB & 1023;
        *(u16x4*)(vtws + (bh * HD + d) * NSEQ + n0) = pk;
    } else {
        #pragma unroll
        for (int v = 0; v < 4; ++v) {
            int n = (mB + v) & 1023;
            float val = acc[v];
            if (which == 0) qws[(bh * NSEQ + n) * HD + d] = f2bf(val * 0.125f);
            else            kws[(bh * NSEQ + n) * HD + d] = f2bf(val);
        }
    }
}

// ---------------------------------------------------------------------------
// K2: k_fattn — fused flash attention per (bh, 32-row i-tile).
//   wave w owns j-quarter: S = mfma(K, q) in 128 VGPRs (swapped operands ->
//   per-i stats lane-local).  Cross-wave softmax merge via 1 KB LDS exchange.
//   P scaled+packed bf16 -> 64 KB swizzled LDS; P copy-out issued BEFORE PV
//   so the 72 KB of stores drain under PV's MFMAs (T14).
// grid 1024 (XCD-pinned bh), block 256.
// ---------------------------------------------------------------------------
__global__ __launch_bounds__(256, 2) void k_fattn(
    const unsigned short* __restrict__ qws, const unsigned short* __restrict__ kws,
    const unsigned short* __restrict__ vtws,
    unsigned short* __restrict__ attnw, float* __restrict__ outv)
{
    __shared__ unsigned short Pl[32 * 1024];   // 64 KB P [i-local][j] swizzled
    __shared__ float mlb[4][2][16][2];         // [wave][i-half][lr][{max,sum}]
    int lane = threadIdx.x & 63, wave = threadIdx.x >> 6;
    int lr = lane & 15, lg = lane >> 4;
    int L = blockIdx.x;
    int bh = (L & 7) * 4 + ((L >> 3) & 3);   // XCD-pinned: K/V L2-resident
    int i0 = (L >> 5) * 32;

    auto paddr = [&](int r, int jb) -> char* {
        unsigned mask = (unsigned)(((r & 7) << 4) | ((r & 3) << 7));
        return (char*)Pl + (unsigned)(r * 2048) + ((unsigned)jb ^ mask);
    };

    // q fragments (B operand: B-row = i)
    s16x8 qf[2][2];
    #pragma unroll
    for (int m = 0; m < 2; ++m) {
        const unsigned short* qrow = qws + (bh * NSEQ + i0 + m * 16 + lr) * HD;
        qf[m][0] = *(const s16x8*)(qrow + lg * 8);
        qf[m][1] = *(const s16x8*)(qrow + 32 + lg * 8);
    }

    // ---- phase A: S for this wave's j-quarter, in registers ----
    f32x4 s[16][2];
    #pragma unroll
    for (int jc = 0; jc < 16; ++jc) {
        const unsigned short* krow =
            kws + (bh * NSEQ + wave * 256 + jc * 16 + lr) * HD + lg * 8;
        s16x8 kf0 = *(const s16x8*)(krow);
        s16x8 kf1 = *(const s16x8*)(krow + 32);
        #pragma unroll
        for (int m = 0; m < 2; ++m) {
            f32x4 acc = {0.f, 0.f, 0.f, 0.f};
            acc = mfma16(kf0, qf[m][0], acc);
            s[jc][m] = mfma16(kf1, qf[m][1], acc);
        }
    }

    // wave-local stats per i
    float mx[2], sm[2];
    #pragma unroll
    for (int m = 0; m < 2; ++m) {
        float v = -3.0e38f;
        #pragma unroll
        for (int jc = 0; jc < 16; ++jc) {
            f32x4 t = s[jc][m];
            v = fmaxf(v, fmaxf(fmaxf(t[0], t[1]), fmaxf(t[2], t[3])));
        }
        v = fmaxf(v, __shfl_xor(v, 16));
        v = fmaxf(v, __shfl_xor(v, 32));
        mx[m] = v;
    }
    #pragma unroll
    for (int m = 0; m < 2; ++m) {
        float sum = 0.f;
        #pragma unroll
        for (int jc = 0; jc < 16; ++jc) {
            f32x4 t = s[jc][m];
            #pragma unroll
            for (int u = 0; u < 4; ++u) { t[u] = __expf(t[u] - mx[m]); sum += t[u]; }
            s[jc][m] = t;
        }
        sum += __shfl_xor(sum, 16);
        sum += __shfl_xor(sum, 32);
        sm[m] = sum;
    }
    if (lg == 0) {
        #pragma unroll
        for (int m = 0; m < 2; ++m) {
            mlb[wave][m][lr][0] = mx[m];
            mlb[wave][m][lr][1] = sm[m];
        }
    }
    __syncthreads();

    // global M, L across the 4 waves; per-wave normalization factor
    float f[2];
    #pragma unroll
    for (int m = 0; m < 2; ++m) {
        float M = -3.0e38f;
        #pragma unroll
        for (int w = 0; w < 4; ++w) M = fmaxf(M, mlb[w][m][lr][0]);
        float Ls = 0.f;
        #pragma unroll
        for (int w = 0; w < 4; ++w)
            Ls += mlb[w][m][lr][1] * __expf(mlb[w][m][lr][0] - M);
        f[m] = __expf(mx[m] - M) / Ls;
    }

    // scale + pack bf16 -> LDS P (wave-private j columns, disjoint)
    #pragma unroll
    for (int jc = 0; jc < 16; ++jc) {
        #pragma unroll
        for (int m = 0; m < 2; ++m) {
            f32x4 t = s[jc][m];
            unsigned lo = (unsigned)f2bf(t[0] * f[m]) | ((unsigned)f2bf(t[1] * f[m]) << 16);
            unsigned hi = (unsigned)f2bf(t[2] * f[m]) | ((unsigned)f2bf(t[3] * f[m]) << 16);
            u32x2 pk = {lo, hi};
            int r  = m * 16 + lr;
            int jb = (wave * 512) + (jc * 32) + (lg * 8);
            *(u32x2*)paddr(r, jb) = pk;
        }
    }
    __syncthreads();

    // ---- P copy-out FIRST: stores drain under the PV MFMAs below ----
    #pragma unroll
    for (int r8 = 0; r8 < 8; ++r8) {
        int r = wave * 8 + r8;
        unsigned short* grow = attnw + ((size_t)(i0 + r) * BH + bh) * NSEQ;
        #pragma unroll
        for (int half = 0; half < 2; ++half) {
            int j = half * 512 + lane * 8;
            s16x8 val = *(s16x8*)paddr(r, j * 2);
            *(s16x8*)(grow + j) = val;
        }
    }

    // ---- phase B: PV; wave owns d-16 (all j from LDS) ----
    int d0 = wave * 16;
    const unsigned short* vrow = vtws + (bh * HD + d0 + lr) * NSEQ + lg * 8;
    f32x4 o0 = {0.f, 0.f, 0.f, 0.f};
    f32x4 o1 = {0.f, 0.f, 0.f, 0.f};
    #pragma unroll
    for (int kt = 0; kt < 32; ++kt) {
        s16x8 bf = *(const s16x8*)(vrow + kt * 32);
        s16x8 a0 = *(s16x8*)paddr(lr,      kt * 64 + lg * 16);
        s16x8 a1 = *(s16x8*)paddr(16 + lr, kt * 64 + lg * 16);
        o0 = mfma16(a0, bf, o0);
        o1 = mfma16(a1, bf, o1);
    }
    float* orow = outv + (bh * NSEQ + i0) * HD;
    #pragma unroll
    for (int v = 0; v < 4; ++v) {
        orow[(lg * 4 + v) * HD + d0 + lr]      = o0[v];
        orow[(16 + lg * 4 + v) * HD + d0 + lr] = o1[v];
    }
}

// ---------------------------------------------------------------------------
// K3 v2: k_pe — barrier-free VALU streaming.
// Per block (one i): stage P[i] = attn[i][32bh][1024j] (contiguous 64 KB) into
// padded LDS once; then 512 threads = (bh, c-pair) stream pe[i] linearly with
// f32x2 loads + fmac.  No MFMA, no transpose, no loop barriers.
// LDS rows padded to 1032 elems -> 4 bh-rows/wave hit disjoint banks;
// 16-lane groups share bh -> broadcast.  pe row (128 B) fully coalesced.
// grid 1024, block 512.
// ---------------------------------------------------------------------------
__global__ __launch_bounds__(512) void k_pe(
    const unsigned short* __restrict__ attnw, const float* __restrict__ pe,
    float* __restrict__ pes)
{
    __shared__ unsigned short Pl[32 * 1032];   // 64.5 KB padded
    int i = blockIdx.x;
    int tid = threadIdx.x;

    // stage: 32768 bf16, 512 thr x 8 elems x 8 iters, coalesced 16B
    const unsigned short* src = attnw + (size_t)i * BH * NSEQ;
    #pragma unroll
    for (int it = 0; it < 8; ++it) {
        int flat = (it * 512 + tid) * 8;
        int bh = flat >> 10, j = flat & 1023;
        *(s16x8*)&Pl[bh * 1032 + j] = *(const s16x8*)(src + flat);
    }
    __syncthreads();

    int bh = tid >> 4;          // 0..31
    int ch = tid & 15;          // c-pair: c = ch*2, ch*2+1
    const float* pei = pe + (size_t)i * NSEQ * PEC + ch * 2;
    const unsigned short* prow = &Pl[bh * 1032];

    float a0 = 0.f, a1 = 0.f;
    #pragma unroll 4
    for (int j8 = 0; j8 < 128; ++j8) {
        s16x8 pv8 = *(const s16x8*)(prow + j8 * 8);   // ds_read_b128, bcast
        #pragma unroll
        for (int u = 0; u < 8; ++u) {
            float p = bf2f(pv8[u]);
            f32x2 w = *(const f32x2*)(pei + (j8 * 8 + u) * PEC);
            a0 += p * w[0];
            a1 += p * w[1];
        }
    }
    float* dst = pes + ((size_t)bh * NSEQ + i) * PEC + ch * 2;
    dst[0] = a0;
    dst[1] = a1;
}

// ---------------------------------------------------------------------------
// K4: t[b][n][h*64+d] = outv + pes @ Wpe^T + bpe   (bf16 packed)
// ---------------------------------------------------------------------------
__global__ __launch_bounds__(256) void k_comb(
    const float* __restrict__ outv, const float* __restrict__ pes,
    const float* __restrict__ Wpe, const float* __restrict__ bpe,
    unsigned short* __restrict__ tws)
{
    __shared__ float wpe_s[HD * PEC];
    __shared__ float bpe_s[HD];
    int tid = threadIdx.x;
    for (int idx = tid; idx < HD * PEC; idx += 256) wpe_s[idx] = Wpe[idx];
    if (tid < HD) bpe_s[tid] = bpe[tid];
    __syncthreads();

    int bh = blockIdx.y;
    int n  = blockIdx.x * 32 + (tid >> 3);
    int d0 = (tid & 7) * 8;
    int b = bh >> 3, h = bh & 7;

    float pr[PEC];
    const float* prow = pes + (bh * NSEQ + n) * PEC;
    #pragma unroll
    for (int c = 0; c < PEC; c += 4) {
        f32x4 t = *(const f32x4*)(prow + c);
        pr[c] = t[0]; pr[c + 1] = t[1]; pr[c + 2] = t[2]; pr[c + 3] = t[3];
    }
    const float* ovp = outv + (bh * NSEQ + n) * HD + d0;
    s16x8 pk;
    #pragma unroll
    for (int dd = 0; dd < 8; ++dd) {
        float acc = bpe_s[d0 + dd] + ovp[dd];
        const float* wrow = &wpe_s[(d0 + dd) * PEC];
        #pragma unroll
        for (int c = 0; c < PEC; ++c) acc += pr[c] * wrow[c];
        pk[dd] = (short)f2bf(acc);
    }
    *(s16x8*)(tws + (b * NSEQ + n) * INNER + h * HD + d0) = pk;
}

// ---------------------------------------------------------------------------
// K5: out[b][n][:] = t @ Wproj^T    (4096 x 128, K=512)
// ---------------------------------------------------------------------------
__global__ __launch_bounds__(256) void k_proj(
    const unsigned short* __restrict__ tws, const float* __restrict__ Wproj,
    float* __restrict__ out)
{
    int lane = threadIdx.x & 63, wave = threadIdx.x >> 6;
    int lr = lane & 15, lg = lane >> 4;
    int n0 = (blockIdx.x * 4 + wave) * 16;
    int m0 = blockIdx.y * 16;
    const unsigned short* arow = tws + (m0 + lr) * INNER;
    const float* brow = Wproj + (n0 + lr) * INNER;
    s16x8 afr[16];
    #pragma unroll
    for (int kt = 0; kt < 16; ++kt)
        afr[kt] = *(const s16x8*)(arow + kt * 32 + lg * 8);
    f32x4 acc = {0.f, 0.f, 0.f, 0.f};
    #pragma unroll
    for (int kt = 0; kt < 16; ++kt) {
        s16x8 bfr = load8bf(brow + kt * 32 + lg * 8);
        acc = mfma16(afr[kt], bfr, acc);
    }
    #pragma unroll
    for (int v = 0; v < 4; ++v)
        out[(m0 + lg * 4 + v) * DIM + n0 + lr] = acc[v];
}

// ---------------------------------------------------------------------------
// Workspace layout (92 MiB total):
//   [ 0,  4) MiB q_ws   bf16 [bh][n][64]
//   [ 4,  8) MiB k_ws   bf16 [bh][n][64]
//   [ 8, 12) MiB vT_ws  bf16 [bh][64][n]
//   [12, 76) MiB attn   bf16 [i][bh][j]   (normalized P)
//   [76, 84) MiB outv   f32  [bh][n][64]
//   [84, 88) MiB pes    f32  [bh][n][32]
//   [88, 92) MiB t      bf16 [b][n][512]
// ---------------------------------------------------------------------------
extern "C" void kernel_launch(void* const* d_in, const int* in_sizes, int n_in,
                              void* d_out, int out_size, void* d_ws, size_t ws_size,
                              hipStream_t stream)
{
    const float* x     = (const float*)d_in[0];
    const float* pe    = (const float*)d_in[1];
    const float* Wq    = (const float*)d_in[2];
    const float* Wk    = (const float*)d_in[3];
    const float* Wv    = (const float*)d_in[4];
    const float* bv    = (const float*)d_in[5];
    const float* Wproj = (const float*)d_in[6];
    const float* Wpe   = (const float*)d_in[7];
    const float* bpe   = (const float*)d_in[8];
    float* out = (float*)d_out;

    char* ws = (char*)d_ws;
    unsigned short* qws  = (unsigned short*)(ws);
    unsigned short* kws  = (unsigned short*)(ws + ( 4u << 20));
    unsigned short* vtws = (unsigned short*)(ws + ( 8u << 20));
    unsigned short* attn = (unsigned short*)(ws + (12u << 20));
    float*          outv = (float*)         (ws + (76u << 20));
    float*          pes  = (float*)         (ws + (84u << 20));
    unsigned short* tws  = (unsigned short*)(ws + (88u << 20));

    k_qkv  <<<dim3(24, 256), 256, 0, stream>>>(x, Wq, Wk, Wv, bv, qws, kws, vtws);
    k_fattn<<<dim3(1024),    256, 0, stream>>>(qws, kws, vtws, attn, outv);
    k_pe   <<<dim3(1024),    512, 0, stream>>>(attn, pe, pes);
    k_comb <<<dim3(32, 32),  256, 0, stream>>>(outv, pes, Wpe, bpe, tws);
    k_proj <<<dim3(2, 256),  256, 0, stream>>>(tws, Wproj, out);
}

// Round 9
// 163.595 us; speedup vs baseline: 2.2001x; 2.2001x over previous
//
#include <hip/hip_runtime.h>
#include <hip/hip_bf16.h>

#define DIM   128
#define NH    8
#define INNER 512
#define HD    64
#define BSZ   4
#define NSEQ  1024
#define PEC   32
#define BH    32   // BSZ*NH

typedef __attribute__((ext_vector_type(4))) float f32x4;
typedef __attribute__((ext_vector_type(2))) float f32x2;
typedef __attribute__((ext_vector_type(8))) short s16x8;
typedef __attribute__((ext_vector_type(4))) unsigned short u16x4;
typedef __attribute__((ext_vector_type(2))) unsigned int u32x2;

__device__ __forceinline__ unsigned short f2bf(float f) {
    unsigned u = __float_as_uint(f);
    u += 0x7fffu + ((u >> 16) & 1u);
    return (unsigned short)(u >> 16);
}

__device__ __forceinline__ float bf2f(short s) {
    return __uint_as_float(((unsigned)(unsigned short)s) << 16);
}

__device__ __forceinline__ s16x8 load8bf(const float* p) {
    f32x4 a = *(const f32x4*)p;
    f32x4 b = *(const f32x4*)(p + 4);
    s16x8 r;
    r[0] = (short)f2bf(a[0]); r[1] = (short)f2bf(a[1]);
    r[2] = (short)f2bf(a[2]); r[3] = (short)f2bf(a[3]);
    r[4] = (short)f2bf(b[0]); r[5] = (short)f2bf(b[1]);
    r[6] = (short)f2bf(b[2]); r[7] = (short)f2bf(b[3]);
    return r;
}

__device__ __forceinline__ f32x4 mfma16(s16x8 a, s16x8 b, f32x4 c) {
    return __builtin_amdgcn_mfma_f32_16x16x32_bf16(a, b, c, 0, 0, 0);
}

// ---------------------------------------------------------------------------
// K1: q/k/v projections.  q_ws,k_ws: bf16 [bh][n][d]  (q pre-scaled by 1/8)
//     vT_ws: bf16 [bh][d][n]  (transposed, bias added)
// ---------------------------------------------------------------------------
__global__ __launch_bounds__(256) void k_qkv(
    const float* __restrict__ x,
    const float* __restrict__ Wq, const float* __restrict__ Wk,
    const float* __restrict__ Wv, const float* __restrict__ bv,
    unsigned short* __restrict__ qws, unsigned short* __restrict__ kws,
    unsigned short* __restrict__ vtws)
{
    int lane = threadIdx.x & 63, wave = threadIdx.x >> 6;
    int lr = lane & 15, lg = lane >> 4;
    int ct   = blockIdx.x * 4 + wave;   // 0..95 column tile over 1536 cols
    int col0 = ct * 16;
    int m0   = blockIdx.y * 16;

    s16x8 a[4];
    const float* xrow = x + (m0 + lr) * DIM;
    #pragma unroll
    for (int kt = 0; kt < 4; ++kt) a[kt] = load8bf(xrow + kt * 32 + lg * 8);

    const float* W; int cbase; int which = col0 >> 9;
    if (which == 0)      { W = Wq; cbase = col0; }
    else if (which == 1) { W = Wk; cbase = col0 - 512; }
    else                 { W = Wv; cbase = col0 - 1024; }

    const float* wrow = W + (cbase + lr) * DIM;
    s16x8 bfr[4];
    #pragma unroll
    for (int kt = 0; kt < 4; ++kt) bfr[kt] = load8bf(wrow + kt * 32 + lg * 8);
    f32x4 acc = {0.f, 0.f, 0.f, 0.f};
    #pragma unroll
    for (int kt = 0; kt < 4; ++kt) acc = mfma16(a[kt], bfr[kt], acc);

    int colW = cbase + lr;          // 0..511 inside this projection
    int h = colW >> 6, d = colW & 63;
    int mB = m0 + lg * 4;           // 4 consecutive rows, same batch
    int b  = mB >> 10;
    int bh = b * NH + h;
    if (which == 2) {
        float bias = bv[colW];
        u16x4 pk;
        #pragma unroll
        for (int v = 0; v < 4; ++v) pk[v] = f2bf(acc[v] + bias);
        int n0 = mB & 1023;
        *(u16x4*)(vtws + (bh * HD + d) * NSEQ + n0) = pk;
    } else {
        #pragma unroll
        for (int v = 0; v < 4; ++v) {
            int n = (mB + v) & 1023;
            float val = acc[v];
            if (which == 0) qws[(bh * NSEQ + n) * HD + d] = f2bf(val * 0.125f);
            else            kws[(bh * NSEQ + n) * HD + d] = f2bf(val);
        }
    }
}

// ---------------------------------------------------------------------------
// K2: k_fattn — fused flash attention per (bh, 32-row i-tile).
//   S = mfma(K, q) in 128 VGPRs; cross-wave softmax via 1 KB LDS exchange;
//   P -> 64 KB swizzled LDS; P copy-out before PV (stores drain under MFMAs);
//   PV d-split from LDS.
// grid 1024 (XCD-pinned bh), block 256.
// ---------------------------------------------------------------------------
__global__ __launch_bounds__(256, 2) void k_fattn(
    const unsigned short* __restrict__ qws, const unsigned short* __restrict__ kws,
    const unsigned short* __restrict__ vtws,
    unsigned short* __restrict__ attnw, float* __restrict__ outv)
{
    __shared__ unsigned short Pl[32 * 1024];   // 64 KB P [i-local][j] swizzled
    __shared__ float mlb[4][2][16][2];         // [wave][i-half][lr][{max,sum}]
    int lane = threadIdx.x & 63, wave = threadIdx.x >> 6;
    int lr = lane & 15, lg = lane >> 4;
    int L = blockIdx.x;
    int bh = (L & 7) * 4 + ((L >> 3) & 3);   // XCD-pinned: K/V L2-resident
    int i0 = (L >> 5) * 32;

    auto paddr = [&](int r, int jb) -> char* {
        unsigned mask = (unsigned)(((r & 7) << 4) | ((r & 3) << 7));
        return (char*)Pl + (unsigned)(r * 2048) + ((unsigned)jb ^ mask);
    };

    // q fragments (B operand: B-row = i)
    s16x8 qf[2][2];
    #pragma unroll
    for (int m = 0; m < 2; ++m) {
        const unsigned short* qrow = qws + (bh * NSEQ + i0 + m * 16 + lr) * HD;
        qf[m][0] = *(const s16x8*)(qrow + lg * 8);
        qf[m][1] = *(const s16x8*)(qrow + 32 + lg * 8);
    }

    // ---- phase A: S for this wave's j-quarter, in registers ----
    f32x4 s[16][2];
    #pragma unroll
    for (int jc = 0; jc < 16; ++jc) {
        const unsigned short* krow =
            kws + (bh * NSEQ + wave * 256 + jc * 16 + lr) * HD + lg * 8;
        s16x8 kf0 = *(const s16x8*)(krow);
        s16x8 kf1 = *(const s16x8*)(krow + 32);
        #pragma unroll
        for (int m = 0; m < 2; ++m) {
            f32x4 acc = {0.f, 0.f, 0.f, 0.f};
            acc = mfma16(kf0, qf[m][0], acc);
            s[jc][m] = mfma16(kf1, qf[m][1], acc);
        }
    }

    // wave-local stats per i
    float mx[2], sm[2];
    #pragma unroll
    for (int m = 0; m < 2; ++m) {
        float v = -3.0e38f;
        #pragma unroll
        for (int jc = 0; jc < 16; ++jc) {
            f32x4 t = s[jc][m];
            v = fmaxf(v, fmaxf(fmaxf(t[0], t[1]), fmaxf(t[2], t[3])));
        }
        v = fmaxf(v, __shfl_xor(v, 16));
        v = fmaxf(v, __shfl_xor(v, 32));
        mx[m] = v;
    }
    #pragma unroll
    for (int m = 0; m < 2; ++m) {
        float sum = 0.f;
        #pragma unroll
        for (int jc = 0; jc < 16; ++jc) {
            f32x4 t = s[jc][m];
            #pragma unroll
            for (int u = 0; u < 4; ++u) { t[u] = __expf(t[u] - mx[m]); sum += t[u]; }
            s[jc][m] = t;
        }
        sum += __shfl_xor(sum, 16);
        sum += __shfl_xor(sum, 32);
        sm[m] = sum;
    }
    if (lg == 0) {
        #pragma unroll
        for (int m = 0; m < 2; ++m) {
            mlb[wave][m][lr][0] = mx[m];
            mlb[wave][m][lr][1] = sm[m];
        }
    }
    __syncthreads();

    // global M, L across the 4 waves; per-wave normalization factor
    float f[2];
    #pragma unroll
    for (int m = 0; m < 2; ++m) {
        float M = -3.0e38f;
        #pragma unroll
        for (int w = 0; w < 4; ++w) M = fmaxf(M, mlb[w][m][lr][0]);
        float Ls = 0.f;
        #pragma unroll
        for (int w = 0; w < 4; ++w)
            Ls += mlb[w][m][lr][1] * __expf(mlb[w][m][lr][0] - M);
        f[m] = __expf(mx[m] - M) / Ls;
    }

    // scale + pack bf16 -> LDS P (wave-private j columns, disjoint)
    #pragma unroll
    for (int jc = 0; jc < 16; ++jc) {
        #pragma unroll
        for (int m = 0; m < 2; ++m) {
            f32x4 t = s[jc][m];
            unsigned lo = (unsigned)f2bf(t[0] * f[m]) | ((unsigned)f2bf(t[1] * f[m]) << 16);
            unsigned hi = (unsigned)f2bf(t[2] * f[m]) | ((unsigned)f2bf(t[3] * f[m]) << 16);
            u32x2 pk = {lo, hi};
            int r  = m * 16 + lr;
            int jb = (wave * 512) + (jc * 32) + (lg * 8);
            *(u32x2*)paddr(r, jb) = pk;
        }
    }
    __syncthreads();

    // ---- P copy-out FIRST: stores drain under the PV MFMAs below ----
    #pragma unroll
    for (int r8 = 0; r8 < 8; ++r8) {
        int r = wave * 8 + r8;
        unsigned short* grow = attnw + ((size_t)(i0 + r) * BH + bh) * NSEQ;
        #pragma unroll
        for (int half = 0; half < 2; ++half) {
            int j = half * 512 + lane * 8;
            s16x8 val = *(s16x8*)paddr(r, j * 2);
            *(s16x8*)(grow + j) = val;
        }
    }

    // ---- phase B: PV; wave owns d-16 (all j from LDS) ----
    int d0 = wave * 16;
    const unsigned short* vrow = vtws + (bh * HD + d0 + lr) * NSEQ + lg * 8;
    f32x4 o0 = {0.f, 0.f, 0.f, 0.f};
    f32x4 o1 = {0.f, 0.f, 0.f, 0.f};
    #pragma unroll
    for (int kt = 0; kt < 32; ++kt) {
        s16x8 bf = *(const s16x8*)(vrow + kt * 32);
        s16x8 a0 = *(s16x8*)paddr(lr,      kt * 64 + lg * 16);
        s16x8 a1 = *(s16x8*)paddr(16 + lr, kt * 64 + lg * 16);
        o0 = mfma16(a0, bf, o0);
        o1 = mfma16(a1, bf, o1);
    }
    float* orow = outv + (bh * NSEQ + i0) * HD;
    #pragma unroll
    for (int v = 0; v < 4; ++v) {
        orow[(lg * 4 + v) * HD + d0 + lr]      = o0[v];
        orow[(16 + lg * 4 + v) * HD + d0 + lr] = o1[v];
    }
}

// ---------------------------------------------------------------------------
// K3 v3: k_pe — wave-private, barrier-free MFMA GEMM per i.
//   pes[bh][i][c] = attn[i] (32bh x 1024j) @ pe[i] (1024j x 32c).
//   Wave w owns j-quarter [w*256,(w+1)*256): all 16 attn A-fragments loaded
//   upfront (max MLP); pe staged issue(t+2)/commit(t+1)/consume(t) through a
//   PRIVATE double-buffered LDS tile — zero __syncthreads in the loop
//   (same-wave ds_write->ds_read ordered by compiler lgkmcnt only).
//   Final: 4 partial 32x32 tiles summed via one LDS exchange + 1 barrier.
// grid 1024, block 256 (4 waves).  LDS 36 KB -> 4 blocks/CU.
// ---------------------------------------------------------------------------
__global__ __launch_bounds__(256) void k_pe(
    const unsigned short* __restrict__ attnw, const float* __restrict__ pe,
    float* __restrict__ pes)
{
    __shared__ unsigned short pt[4][2][PEC][40];   // per-wave dbuf pe^T, 20 KB
    __shared__ float part[4][BH][PEC];             // partials, 16 KB
    int i = blockIdx.x;
    int lane = threadIdx.x & 63, wave = threadIdx.x >> 6;
    int lr = lane & 15, lg = lane >> 4;
    int jp = lane & 15, cg = lane >> 4;            // staging roles
    const float* pei = pe + (size_t)i * NSEQ * PEC;
    int jbase = wave * 256;

    // all 16 A-fragments upfront: af[t][mh] = attn[i][mh*16+lr][jbase+t*32+lg*8..]
    s16x8 af[8][2];
    #pragma unroll
    for (int t = 0; t < 8; ++t) {
        #pragma unroll
        for (int mh = 0; mh < 2; ++mh) {
            const unsigned short* ap =
                attnw + ((size_t)i * BH + mh * 16 + lr) * NSEQ + jbase + t * 32 + lg * 8;
            af[t][mh] = *(const s16x8*)ap;
        }
    }

    f32x4 r0, r1, r2, r3;        // pe stage registers (2 j x 8 c per lane)
    auto issue = [&](int t) {
        const float* s0 = pei + (size_t)(jbase + t * 32 + jp * 2) * PEC + cg * 8;
        r0 = *(const f32x4*)(s0);
        r1 = *(const f32x4*)(s0 + 4);
        r2 = *(const f32x4*)(s0 + PEC);
        r3 = *(const f32x4*)(s0 + PEC + 4);
    };
    auto commit = [&](int buf) {   // pack bf16 pairs -> pt[wave][buf][c][j0..1]
        #pragma unroll
        for (int cc = 0; cc < 4; ++cc) {
            unsigned lo = f2bf(r0[cc]), hi = f2bf(r2[cc]);
            *(unsigned*)&pt[wave][buf][cg * 8 + cc][jp * 2] = lo | (hi << 16);
        }
        #pragma unroll
        for (int cc = 0; cc < 4; ++cc) {
            unsigned lo = f2bf(r1[cc]), hi = f2bf(r3[cc]);
            *(unsigned*)&pt[wave][buf][cg * 8 + 4 + cc][jp * 2] = lo | (hi << 16);
        }
    };

    f32x4 acc00 = {0.f,0.f,0.f,0.f}, acc01 = {0.f,0.f,0.f,0.f};
    f32x4 acc10 = {0.f,0.f,0.f,0.f}, acc11 = {0.f,0.f,0.f,0.f};

    issue(0); commit(0);
    issue(1);
    #pragma unroll
    for (int t = 0; t < 8; ++t) {
        int cur = t & 1;
        s16x8 bf0 = *(const s16x8*)&pt[wave][cur][lr][lg * 8];
        s16x8 bf1 = *(const s16x8*)&pt[wave][cur][16 + lr][lg * 8];
        acc00 = mfma16(af[t][0], bf0, acc00);
        acc01 = mfma16(af[t][0], bf1, acc01);
        acc10 = mfma16(af[t][1], bf0, acc10);
        acc11 = mfma16(af[t][1], bf1, acc11);
        if (t < 7) {
            commit(cur ^ 1);         // regs currently hold tile t+1
            if (t < 6) issue(t + 2);
        }
    }

    // partial store: C row = bh-in-half = lg*4+v, col = c-in-half = lr
    #pragma unroll
    for (int v = 0; v < 4; ++v) {
        part[wave][lg * 4 + v][lr]           = acc00[v];
        part[wave][lg * 4 + v][16 + lr]      = acc01[v];
        part[wave][16 + lg * 4 + v][lr]      = acc10[v];
        part[wave][16 + lg * 4 + v][16 + lr] = acc11[v];
    }
    __syncthreads();

    int tid = threadIdx.x;
    int bh = tid >> 3, c0 = (tid & 7) * 4;
    f32x4 s = *(f32x4*)&part[0][bh][c0];
    #pragma unroll
    for (int w = 1; w < 4; ++w) {
        f32x4 q = *(f32x4*)&part[w][bh][c0];
        s[0] += q[0]; s[1] += q[1]; s[2] += q[2]; s[3] += q[3];
    }
    *(f32x4*)(pes + ((size_t)bh * NSEQ + i) * PEC + c0) = s;
}

// ---------------------------------------------------------------------------
// K4: t[b][n][h*64+d] = outv + pes @ Wpe^T + bpe   (bf16 packed)
// ---------------------------------------------------------------------------
__global__ __launch_bounds__(256) void k_comb(
    const float* __restrict__ outv, const float* __restrict__ pes,
    const float* __restrict__ Wpe, const float* __restrict__ bpe,
    unsigned short* __restrict__ tws)
{
    __shared__ float wpe_s[HD * PEC];
    __shared__ float bpe_s[HD];
    int tid = threadIdx.x;
    for (int idx = tid; idx < HD * PEC; idx += 256) wpe_s[idx] = Wpe[idx];
    if (tid < HD) bpe_s[tid] = bpe[tid];
    __syncthreads();

    int bh = blockIdx.y;
    int n  = blockIdx.x * 32 + (tid >> 3);
    int d0 = (tid & 7) * 8;
    int b = bh >> 3, h = bh & 7;

    float pr[PEC];
    const float* prow = pes + (bh * NSEQ + n) * PEC;
    #pragma unroll
    for (int c = 0; c < PEC; c += 4) {
        f32x4 t = *(const f32x4*)(prow + c);
        pr[c] = t[0]; pr[c + 1] = t[1]; pr[c + 2] = t[2]; pr[c + 3] = t[3];
    }
    const float* ovp = outv + (bh * NSEQ + n) * HD + d0;
    s16x8 pk;
    #pragma unroll
    for (int dd = 0; dd < 8; ++dd) {
        float acc = bpe_s[d0 + dd] + ovp[dd];
        const float* wrow = &wpe_s[(d0 + dd) * PEC];
        #pragma unroll
        for (int c = 0; c < PEC; ++c) acc += pr[c] * wrow[c];
        pk[dd] = (short)f2bf(acc);
    }
    *(s16x8*)(tws + (b * NSEQ + n) * INNER + h * HD + d0) = pk;
}

// ---------------------------------------------------------------------------
// K5: out[b][n][:] = t @ Wproj^T    (4096 x 128, K=512)
// ---------------------------------------------------------------------------
__global__ __launch_bounds__(256) void k_proj(
    const unsigned short* __restrict__ tws, const float* __restrict__ Wproj,
    float* __restrict__ out)
{
    int lane = threadIdx.x & 63, wave = threadIdx.x >> 6;
    int lr = lane & 15, lg = lane >> 4;
    int n0 = (blockIdx.x * 4 + wave) * 16;
    int m0 = blockIdx.y * 16;
    const unsigned short* arow = tws + (m0 + lr) * INNER;
    const float* brow = Wproj + (n0 + lr) * INNER;
    s16x8 afr[16];
    #pragma unroll
    for (int kt = 0; kt < 16; ++kt)
        afr[kt] = *(const s16x8*)(arow + kt * 32 + lg * 8);
    f32x4 acc = {0.f, 0.f, 0.f, 0.f};
    #pragma unroll
    for (int kt = 0; kt < 16; ++kt) {
        s16x8 bfr = load8bf(brow + kt * 32 + lg * 8);
        acc = mfma16(afr[kt], bfr, acc);
    }
    #pragma unroll
    for (int v = 0; v < 4; ++v)
        out[(m0 + lg * 4 + v) * DIM + n0 + lr] = acc[v];
}

// ---------------------------------------------------------------------------
// Workspace layout (92 MiB total):
//   [ 0,  4) MiB q_ws   bf16 [bh][n][64]
//   [ 4,  8) MiB k_ws   bf16 [bh][n][64]
//   [ 8, 12) MiB vT_ws  bf16 [bh][64][n]
//   [12, 76) MiB attn   bf16 [i][bh][j]   (normalized P)
//   [76, 84) MiB outv   f32  [bh][n][64]
//   [84, 88) MiB pes    f32  [bh][n][32]
//   [88, 92) MiB t      bf16 [b][n][512]
// ---------------------------------------------------------------------------
extern "C" void kernel_launch(void* const* d_in, const int* in_sizes, int n_in,
                              void* d_out, int out_size, void* d_ws, size_t ws_size,
                              hipStream_t stream)
{
    const float* x     = (const float*)d_in[0];
    const float* pe    = (const float*)d_in[1];
    const float* Wq    = (const float*)d_in[2];
    const float* Wk    = (const float*)d_in[3];
    const float* Wv    = (const float*)d_in[4];
    const float* bv    = (const float*)d_in[5];
    const float* Wproj = (const float*)d_in[6];
    const float* Wpe   = (const float*)d_in[7];
    const float* bpe   = (const float*)d_in[8];
    float* out = (float*)d_out;

    char* ws = (char*)d_ws;
    unsigned short* qws  = (unsigned short*)(ws);
    unsigned short* kws  = (unsigned short*)(ws + ( 4u << 20));
    unsigned short* vtws = (unsigned short*)(ws + ( 8u << 20));
    unsigned short* attn = (unsigned short*)(ws + (12u << 20));
    float*          outv = (float*)         (ws + (76u << 20));
    float*          pes  = (float*)         (ws + (84u << 20));
    unsigned short* tws  = (unsigned short*)(ws + (88u << 20));

    k_qkv  <<<dim3(24, 256), 256, 0, stream>>>(x, Wq, Wk, Wv, bv, qws, kws, vtws);
    k_fattn<<<dim3(1024),    256, 0, stream>>>(qws, kws, vtws, attn, outv);
    k_pe   <<<dim3(1024),    256, 0, stream>>>(attn, pe, pes);
    k_comb <<<dim3(32, 32),  256, 0, stream>>>(outv, pes, Wpe, bpe, tws);
    k_proj <<<dim3(2, 256),  256, 0, stream>>>(tws, Wproj, out);
}